// Round 1
// baseline (998.897 us; speedup 1.0000x reference)
//
#include <hip/hip_runtime.h>

#define MTOT 32768   // B*N
#define KDIM 512     // D
#define CDIM 2048    // C
#define BM   128
#define BN   256
#define BK   16
#define NT   256     // threads per block

// ---------------- codebook inverse norms ----------------
__global__ __launch_bounds__(256, 1)
void vq_norm_kernel(const float* __restrict__ embed, float* __restrict__ inv_norm) {
    const int row  = blockIdx.x * 4 + (threadIdx.x >> 6);
    const int lane = threadIdx.x & 63;
    const float* e = embed + (size_t)row * KDIM;
    float ss = 0.f;
#pragma unroll
    for (int p = 0; p < 8; ++p) {
        float v = e[lane + 64 * p];
        ss = fmaf(v, v, ss);
    }
#pragma unroll
    for (int off = 32; off >= 1; off >>= 1)
        ss += __shfl_xor(ss, off, 64);
    if (lane == 0) inv_norm[row] = 1.0f / fmaxf(sqrtf(ss), 1e-12f);
}

// ---------------- fused gemm + argmax + gather ----------------
__global__ __launch_bounds__(NT, 1)
void vq_main_kernel(const float* __restrict__ x,
                    const float* __restrict__ embed,
                    const float* __restrict__ inv_norm,
                    float* __restrict__ out_q,
                    float* __restrict__ out_i) {
    __shared__ float As[BK][BM + 4];   // k-major, +4 pad keeps 16B row alignment
    __shared__ float Bs[BK][BN + 4];
    __shared__ float best_val[BM];
    __shared__ int   best_idx[BM];

    const int tid = threadIdx.x;
    const int m0  = blockIdx.x * BM;
    const int ty  = tid >> 5;   // 0..7   -> 16 rows each
    const int tx  = tid & 31;   // 0..31  -> 8 cols each

    if (tid < BM) { best_val[tid] = -3.0e38f; best_idx[tid] = 0; }

    float acc[16][8];

    for (int n0 = 0; n0 < CDIM; n0 += BN) {
#pragma unroll
        for (int i = 0; i < 16; ++i)
#pragma unroll
            for (int j = 0; j < 8; ++j) acc[i][j] = 0.f;

        for (int kt = 0; kt < KDIM; kt += BK) {
            __syncthreads();   // protect LDS reuse (also covers best_* init)
            // stage A tile (x), transposed to k-major
#pragma unroll
            for (int l = 0; l < 2; ++l) {
                int f  = tid + l * NT;          // 0..511
                int m  = f >> 2;                // 0..127
                int k4 = (f & 3) << 2;          // 0,4,8,12
                const float4 v = *(const float4*)&x[(size_t)(m0 + m) * KDIM + kt + k4];
                As[k4 + 0][m] = v.x; As[k4 + 1][m] = v.y;
                As[k4 + 2][m] = v.z; As[k4 + 3][m] = v.w;
            }
            // stage B tile (embed * inv_norm), transposed to k-major
#pragma unroll
            for (int l = 0; l < 4; ++l) {
                int f  = tid + l * NT;          // 0..1023
                int c  = f >> 2;                // 0..255
                int k4 = (f & 3) << 2;
                float s = inv_norm[n0 + c];
                const float4 v = *(const float4*)&embed[(size_t)(n0 + c) * KDIM + kt + k4];
                Bs[k4 + 0][c] = v.x * s; Bs[k4 + 1][c] = v.y * s;
                Bs[k4 + 2][c] = v.z * s; Bs[k4 + 3][c] = v.w * s;
            }
            __syncthreads();

#pragma unroll 4
            for (int k = 0; k < BK; ++k) {
                float a[16], b[8];
                *(float4*)&a[0]  = *(const float4*)&As[k][ty * 16 + 0];
                *(float4*)&a[4]  = *(const float4*)&As[k][ty * 16 + 4];
                *(float4*)&a[8]  = *(const float4*)&As[k][ty * 16 + 8];
                *(float4*)&a[12] = *(const float4*)&As[k][ty * 16 + 12];
                *(float4*)&b[0]  = *(const float4*)&Bs[k][tx * 8 + 0];
                *(float4*)&b[4]  = *(const float4*)&Bs[k][tx * 8 + 4];
#pragma unroll
                for (int i = 0; i < 16; ++i)
#pragma unroll
                    for (int j = 0; j < 8; ++j)
                        acc[i][j] = fmaf(a[i], b[j], acc[i][j]);
            }
        }

        // per-row argmax for this N-tile
#pragma unroll
        for (int i = 0; i < 16; ++i) {
            float v = acc[i][0];
            int  jj = 0;
#pragma unroll
            for (int j = 1; j < 8; ++j)
                if (acc[i][j] > v) { v = acc[i][j]; jj = j; }
            int col = n0 + tx * 8 + jj;
#pragma unroll
            for (int off = 16; off >= 1; off >>= 1) {
                float ov = __shfl_xor(v, off, 64);
                int   oc = __shfl_xor(col, off, 64);
                if (ov > v || (ov == v && oc < col)) { v = ov; col = oc; }
            }
            if (tx == 0) {
                int r = (ty << 4) + i;
                if (v > best_val[r] ||
                    (v == best_val[r] && col < best_idx[r])) {
                    best_val[r] = v;
                    best_idx[r] = col;
                }
            }
        }
    }

    __syncthreads();
    // indices (as float, matching f32 output buffer)
    if (tid < BM) out_i[m0 + tid] = (float)best_idx[tid];

    // gather raw embed rows -> quantize output
#pragma unroll 1
    for (int rp = 0; rp < BM; rp += 2) {
        int r    = rp + (tid >> 7);     // two rows per iteration
        int slot = tid & 127;           // 128 float4 slots = 512 floats
        int src  = best_idx[r];
        const float4 v = *(const float4*)&embed[(size_t)src * KDIM + slot * 4];
        *(float4*)&out_q[(size_t)(m0 + r) * KDIM + slot * 4] = v;
    }
}

extern "C" void kernel_launch(void* const* d_in, const int* in_sizes, int n_in,
                              void* d_out, int out_size, void* d_ws, size_t ws_size,
                              hipStream_t stream) {
    const float* x     = (const float*)d_in[0];
    const float* embed = (const float*)d_in[1];
    float* inv_norm = (float*)d_ws;                       // C floats = 8 KB
    float* out_q    = (float*)d_out;                      // [M, D]
    float* out_i    = (float*)d_out + (size_t)MTOT * KDIM; // [M]

    vq_norm_kernel<<<CDIM / 4, 256, 0, stream>>>(embed, inv_norm);
    vq_main_kernel<<<MTOT / BM, NT, 0, stream>>>(x, embed, inv_norm, out_q, out_i);
}

// Round 2
// 851.860 us; speedup vs baseline: 1.1726x; 1.1726x over previous
//
#include <hip/hip_runtime.h>

#define MTOT 32768   // B*N
#define KDIM 512     // D
#define CDIM 2048    // C
#define BM   64
#define BN   256
#define BK   16
#define NT   256     // threads per block

// ---------------- codebook inverse norms ----------------
__global__ __launch_bounds__(256, 1)
void vq_norm_kernel(const float* __restrict__ embed, float* __restrict__ inv_norm) {
    const int row  = blockIdx.x * 4 + (threadIdx.x >> 6);
    const int lane = threadIdx.x & 63;
    const float* e = embed + (size_t)row * KDIM;
    float ss = 0.f;
#pragma unroll
    for (int p = 0; p < 8; ++p) {
        float v = e[lane + 64 * p];
        ss = fmaf(v, v, ss);
    }
#pragma unroll
    for (int off = 32; off >= 1; off >>= 1)
        ss += __shfl_xor(ss, off, 64);
    if (lane == 0) inv_norm[row] = 1.0f / fmaxf(sqrtf(ss), 1e-12f);
}

// ---------------- fused gemm + argmax + gather ----------------
__global__ __launch_bounds__(NT, 2)
void vq_main_kernel(const float* __restrict__ x,
                    const float* __restrict__ embed,
                    const float* __restrict__ inv_norm,
                    float* __restrict__ out_q,
                    float* __restrict__ out_i) {
    __shared__ float As[BK][BM + 4];   // k-major
    __shared__ float Bs[BK][BN + 4];
    __shared__ float best_val[BM];
    __shared__ int   best_idx[BM];

    const int tid = threadIdx.x;
    const int m0  = blockIdx.x * BM;
    const int ty  = tid >> 5;   // 0..7  -> 8 rows each
    const int tx  = tid & 31;   // 0..31 -> cols {tx*4+j, 128+tx*4+j}

    if (tid < BM) { best_val[tid] = -3.0e38f; best_idx[tid] = 0; }

    // staging geometry (fixed per thread)
    const int am  = tid >> 2;           // 0..63  A row
    const int k4  = (tid & 3) << 2;     // 0,4,8,12
    const int bc  = tid >> 2;           // B col base (per l: +64*l)

    float acc[8][8];

    for (int n0 = 0; n0 < CDIM; n0 += BN) {
        // per-tile codebook scales (hoisted out of kt loop)
        float bs0 = inv_norm[n0 + bc +   0];
        float bs1 = inv_norm[n0 + bc +  64];
        float bs2 = inv_norm[n0 + bc + 128];
        float bs3 = inv_norm[n0 + bc + 192];

#pragma unroll
        for (int i = 0; i < 8; ++i)
#pragma unroll
            for (int j = 0; j < 8; ++j) acc[i][j] = 0.f;

        // prologue: prefetch tile kt=0 into registers
        float4 aReg = *(const float4*)&x[(size_t)(m0 + am) * KDIM + k4];
        float4 bReg0 = *(const float4*)&embed[(size_t)(n0 + bc +   0) * KDIM + k4];
        float4 bReg1 = *(const float4*)&embed[(size_t)(n0 + bc +  64) * KDIM + k4];
        float4 bReg2 = *(const float4*)&embed[(size_t)(n0 + bc + 128) * KDIM + k4];
        float4 bReg3 = *(const float4*)&embed[(size_t)(n0 + bc + 192) * KDIM + k4];

        for (int kt = 0; kt < KDIM; kt += BK) {
            __syncthreads();   // LDS free to overwrite
            // regs -> LDS (transposed, k-major)
            As[k4 + 0][am] = aReg.x; As[k4 + 1][am] = aReg.y;
            As[k4 + 2][am] = aReg.z; As[k4 + 3][am] = aReg.w;
            Bs[k4 + 0][bc +   0] = bReg0.x * bs0; Bs[k4 + 1][bc +   0] = bReg0.y * bs0;
            Bs[k4 + 2][bc +   0] = bReg0.z * bs0; Bs[k4 + 3][bc +   0] = bReg0.w * bs0;
            Bs[k4 + 0][bc +  64] = bReg1.x * bs1; Bs[k4 + 1][bc +  64] = bReg1.y * bs1;
            Bs[k4 + 2][bc +  64] = bReg1.z * bs1; Bs[k4 + 3][bc +  64] = bReg1.w * bs1;
            Bs[k4 + 0][bc + 128] = bReg2.x * bs2; Bs[k4 + 1][bc + 128] = bReg2.y * bs2;
            Bs[k4 + 2][bc + 128] = bReg2.z * bs2; Bs[k4 + 3][bc + 128] = bReg2.w * bs2;
            Bs[k4 + 0][bc + 192] = bReg3.x * bs3; Bs[k4 + 1][bc + 192] = bReg3.y * bs3;
            Bs[k4 + 2][bc + 192] = bReg3.z * bs3; Bs[k4 + 3][bc + 192] = bReg3.w * bs3;
            __syncthreads();

            // prefetch NEXT tile while computing this one (T14)
            if (kt + BK < KDIM) {
                int kn = kt + BK + k4;
                aReg  = *(const float4*)&x[(size_t)(m0 + am) * KDIM + kn];
                bReg0 = *(const float4*)&embed[(size_t)(n0 + bc +   0) * KDIM + kn];
                bReg1 = *(const float4*)&embed[(size_t)(n0 + bc +  64) * KDIM + kn];
                bReg2 = *(const float4*)&embed[(size_t)(n0 + bc + 128) * KDIM + kn];
                bReg3 = *(const float4*)&embed[(size_t)(n0 + bc + 192) * KDIM + kn];
            }

#pragma unroll 4
            for (int k = 0; k < BK; ++k) {
                float a[8], b[8];
                *(float4*)&a[0] = *(const float4*)&As[k][ty * 8 + 0];
                *(float4*)&a[4] = *(const float4*)&As[k][ty * 8 + 4];
                *(float4*)&b[0] = *(const float4*)&Bs[k][tx * 4];         // cols tx*4+0..3
                *(float4*)&b[4] = *(const float4*)&Bs[k][128 + tx * 4];   // cols 128+tx*4+0..3
#pragma unroll
                for (int i = 0; i < 8; ++i)
#pragma unroll
                    for (int j = 0; j < 8; ++j)
                        acc[i][j] = fmaf(a[i], b[j], acc[i][j]);
            }
        }

        // per-row argmax for this N-tile
#pragma unroll
        for (int i = 0; i < 8; ++i) {
            float v = acc[i][0];
            int  jj = 0;
#pragma unroll
            for (int j = 1; j < 8; ++j)
                if (acc[i][j] > v) { v = acc[i][j]; jj = j; }
            int col = n0 + ((jj < 4) ? (tx * 4 + jj) : (128 + tx * 4 + (jj - 4)));
#pragma unroll
            for (int off = 16; off >= 1; off >>= 1) {
                float ov = __shfl_xor(v, off, 64);
                int   oc = __shfl_xor(col, off, 64);
                if (ov > v || (ov == v && oc < col)) { v = ov; col = oc; }
            }
            if (tx == 0) {
                int r = ty * 8 + i;
                if (v > best_val[r] ||
                    (v == best_val[r] && col < best_idx[r])) {
                    best_val[r] = v;
                    best_idx[r] = col;
                }
            }
        }
    }

    __syncthreads();
    // indices (as float, f32 output chunk 2)
    if (tid < BM) out_i[m0 + tid] = (float)best_idx[tid];

    // gather raw embed rows -> quantize output
#pragma unroll 1
    for (int rp = 0; rp < BM; rp += 2) {
        int r    = rp + (tid >> 7);     // two rows per iteration
        int slot = tid & 127;           // 128 float4 slots = 512 floats
        int src  = best_idx[r];
        const float4 v = *(const float4*)&embed[(size_t)src * KDIM + slot * 4];
        *(float4*)&out_q[(size_t)(m0 + r) * KDIM + slot * 4] = v;
    }
}

extern "C" void kernel_launch(void* const* d_in, const int* in_sizes, int n_in,
                              void* d_out, int out_size, void* d_ws, size_t ws_size,
                              hipStream_t stream) {
    const float* x     = (const float*)d_in[0];
    const float* embed = (const float*)d_in[1];
    float* inv_norm = (float*)d_ws;                        // C floats = 8 KB
    float* out_q    = (float*)d_out;                       // [M, D]
    float* out_i    = (float*)d_out + (size_t)MTOT * KDIM; // [M]

    vq_norm_kernel<<<CDIM / 4, 256, 0, stream>>>(embed, inv_norm);
    vq_main_kernel<<<MTOT / BM, NT, 0, stream>>>(x, embed, inv_norm, out_q, out_i);
}

// Round 3
// 202.359 us; speedup vs baseline: 4.9363x; 4.2096x over previous
//
#include <hip/hip_runtime.h>

#define MTOT 32768   // B*N
#define KDIM 512     // D
#define CDIM 2048    // C
#define CAP  16      // candidate slots per row
#define TAU  0.032f  // candidate window (~14 sigma of bf16 rounding noise)

// ---- workspace layout (bytes) ----
#define XH_OFF   0u
#define XH_SZ    (MTOT * KDIM * 2u)          // 32 MB bf16
#define EH_OFF   (XH_OFF + XH_SZ)
#define EH_SZ    (CDIM * KDIM * 2u)          // 2 MB bf16
#define INV_OFF  (EH_OFF + EH_SZ)
#define INV_SZ   (CDIM * 4u)
#define CNT_OFF  (INV_OFF + INV_SZ)
#define CNT_SZ   (MTOT * 4u)
#define CAND_OFF (CNT_OFF + CNT_SZ)
#define CAND_SZ  (MTOT * CAP * 4u)
#define WS_NEEDED (CAND_OFF + CAND_SZ)

typedef short  short8 __attribute__((ext_vector_type(8)));
typedef float  f32x4  __attribute__((ext_vector_type(4)));

__device__ inline unsigned short f2bf(float f) {
    unsigned u = __float_as_uint(f);
    return (unsigned short)((u + 0x7FFFu + ((u >> 16) & 1u)) >> 16);  // RTNE
}
__device__ inline unsigned fkey(float f) {          // order-preserving f32->u32
    unsigned u = __float_as_uint(f);
    return (u & 0x80000000u) ? ~u : (u | 0x80000000u);
}
__device__ inline float fkey_inv(unsigned k) {
    unsigned u = (k & 0x80000000u) ? (k ^ 0x80000000u) : ~k;
    return __uint_as_float(u);
}

// ---------------- codebook norms + bf16 normalized codebook ----------------
__global__ __launch_bounds__(256, 1)
void vq_norm_eh_kernel(const float* __restrict__ embed, float* __restrict__ inv_norm,
                       unsigned short* __restrict__ eh) {
    const int row  = blockIdx.x * 4 + (threadIdx.x >> 6);
    const int lane = threadIdx.x & 63;
    const float4 v0 = *(const float4*)&embed[(size_t)row * KDIM + lane * 8];
    const float4 v1 = *(const float4*)&embed[(size_t)row * KDIM + lane * 8 + 4];
    float ss = v0.x*v0.x + v0.y*v0.y + v0.z*v0.z + v0.w*v0.w
             + v1.x*v1.x + v1.y*v1.y + v1.z*v1.z + v1.w*v1.w;
#pragma unroll
    for (int off = 32; off >= 1; off >>= 1) ss += __shfl_xor(ss, off, 64);
    float inv = 1.0f / fmaxf(sqrtf(ss), 1e-12f);
    if (lane == 0) inv_norm[row] = inv;
    short8 o;
    o[0] = (short)f2bf(v0.x * inv); o[1] = (short)f2bf(v0.y * inv);
    o[2] = (short)f2bf(v0.z * inv); o[3] = (short)f2bf(v0.w * inv);
    o[4] = (short)f2bf(v1.x * inv); o[5] = (short)f2bf(v1.y * inv);
    o[6] = (short)f2bf(v1.z * inv); o[7] = (short)f2bf(v1.w * inv);
    *(short8*)&eh[(size_t)row * KDIM + lane * 8] = o;
}

// ---------------- x -> bf16 ----------------
__global__ __launch_bounds__(256, 1)
void vq_convx_kernel(const float* __restrict__ x, unsigned short* __restrict__ xh) {
    const size_t base = ((size_t)blockIdx.x * 256 + threadIdx.x) * 8;
    const float4 a = *(const float4*)&x[base];
    const float4 b = *(const float4*)&x[base + 4];
    short8 o;
    o[0] = (short)f2bf(a.x); o[1] = (short)f2bf(a.y);
    o[2] = (short)f2bf(a.z); o[3] = (short)f2bf(a.w);
    o[4] = (short)f2bf(b.x); o[5] = (short)f2bf(b.y);
    o[6] = (short)f2bf(b.z); o[7] = (short)f2bf(b.w);
    *(short8*)&xh[base] = o;
}

// ---------------- phase 1: bf16 MFMA GEMM + max + candidate window ----------------
// BM=128 rows/block, BN=256 codes/tile (8 tiles), BK=64, 8 waves as 2(m)x4(n),
// each wave 64x64 via 4x4 grid of 16x16x32 MFMA.
__global__ __launch_bounds__(512, 2)
void vq_phase1_kernel(const unsigned short* __restrict__ xh,
                      const unsigned short* __restrict__ eh,
                      unsigned* __restrict__ cnt_g, unsigned* __restrict__ cand_g) {
    __shared__ char ldsA[128 * 128];   // 128 rows x 64 k x 2B (XOR-swizzled)
    __shared__ char ldsB[256 * 128];   // 256 codes x 64 k x 2B
    __shared__ unsigned runmax[128];
    __shared__ unsigned cnt[128];
    __shared__ unsigned cand[128][CAP];

    const int tid  = threadIdx.x;
    const int lane = tid & 63;
    const int wid  = tid >> 6;
    const int wr   = wid >> 2;          // 0..1
    const int wc   = wid & 3;           // 0..3
    const int m0   = blockIdx.x * 128;

    const int laneRow = lane & 15;
    const int laneK   = (lane >> 4) * 16;        // byte offset of k-chunk
    const int swz     = (laneRow & 7) << 4;

    if (tid < 128) { runmax[tid] = fkey(-3.4e38f); cnt[tid] = 0; }

    // staging geometry
    const int aRow = tid >> 2;                   // with l: row = (tid + l*512)>>3... see below
    (void)aRow;

    for (int n0 = 0; n0 < CDIM; n0 += 256) {
        f32x4 acc[4][4];
#pragma unroll
        for (int i = 0; i < 4; ++i)
#pragma unroll
            for (int j = 0; j < 4; ++j) acc[i][j] = (f32x4)0.0f;

        // prefetch kt=0
        short8 pa[2], pb[4];
#pragma unroll
        for (int l = 0; l < 2; ++l) {
            int c = tid + l * 512, row = c >> 3, k8 = c & 7;
            pa[l] = *(const short8*)&xh[(size_t)(m0 + row) * KDIM + k8 * 8];
        }
#pragma unroll
        for (int l = 0; l < 4; ++l) {
            int c = tid + l * 512, code = c >> 3, k8 = c & 7;
            pb[l] = *(const short8*)&eh[(size_t)(n0 + code) * KDIM + k8 * 8];
        }

        for (int kt = 0; kt < KDIM; kt += 64) {
            __syncthreads();
#pragma unroll
            for (int l = 0; l < 2; ++l) {
                int c = tid + l * 512, row = c >> 3, k8 = c & 7;
                int off = (row * 128 + k8 * 16) ^ ((row & 7) << 4);
                *(short8*)(ldsA + off) = pa[l];
            }
#pragma unroll
            for (int l = 0; l < 4; ++l) {
                int c = tid + l * 512, code = c >> 3, k8 = c & 7;
                int off = (code * 128 + k8 * 16) ^ ((code & 7) << 4);
                *(short8*)(ldsB + off) = pb[l];
            }
            __syncthreads();

            if (kt + 64 < KDIM) {   // T14 prefetch next K-tile
                int kn = kt + 64;
#pragma unroll
                for (int l = 0; l < 2; ++l) {
                    int c = tid + l * 512, row = c >> 3, k8 = c & 7;
                    pa[l] = *(const short8*)&xh[(size_t)(m0 + row) * KDIM + kn + k8 * 8];
                }
#pragma unroll
                for (int l = 0; l < 4; ++l) {
                    int c = tid + l * 512, code = c >> 3, k8 = c & 7;
                    pb[l] = *(const short8*)&eh[(size_t)(n0 + code) * KDIM + kn + k8 * 8];
                }
            }

#pragma unroll
            for (int kk = 0; kk < 2; ++kk) {
                short8 af[4], bf[4];
#pragma unroll
                for (int ai = 0; ai < 4; ++ai) {
                    int row = wr * 64 + ai * 16 + laneRow;
                    int off = ((row * 128 + laneK + kk * 64)) ^ swz;
                    af[ai] = *(const short8*)(ldsA + off);
                }
#pragma unroll
                for (int aj = 0; aj < 4; ++aj) {
                    int code = wc * 64 + aj * 16 + laneRow;
                    int off = ((code * 128 + laneK + kk * 64)) ^ swz;
                    bf[aj] = *(const short8*)(ldsB + off);
                }
#pragma unroll
                for (int ai = 0; ai < 4; ++ai)
#pragma unroll
                    for (int aj = 0; aj < 4; ++aj)
                        acc[ai][aj] = __builtin_amdgcn_mfma_f32_16x16x32_bf16(
                            af[ai], bf[aj], acc[ai][aj], 0, 0, 0);
            }
        }

        // per-row max -> runmax (rows r = wr*64 + ai*16 + (lane>>4)*4 + reg)
#pragma unroll
        for (int ai = 0; ai < 4; ++ai) {
#pragma unroll
            for (int r = 0; r < 4; ++r) {
                float v = acc[ai][0][r];
                int   c = 0 * 16 + laneRow;
#pragma unroll
                for (int aj = 1; aj < 4; ++aj) {
                    float x2 = acc[ai][aj][r];
                    if (x2 > v) { v = x2; c = aj * 16 + laneRow; }
                }
#pragma unroll
                for (int off = 8; off >= 1; off >>= 1) {
                    float ov = __shfl_xor(v, off, 64);
                    int   oc = __shfl_xor(c, off, 64);
                    if (ov > v || (ov == v && oc < c)) { v = ov; c = oc; }
                }
                if (laneRow == 0) {
                    int rl = wr * 64 + ai * 16 + (lane >> 4) * 4 + r;
                    atomicMax(&runmax[rl], fkey(v));
                }
            }
        }
        __syncthreads();

        // candidate sweep against running max - TAU
#pragma unroll
        for (int ai = 0; ai < 4; ++ai) {
#pragma unroll
            for (int r = 0; r < 4; ++r) {
                int rl = wr * 64 + ai * 16 + (lane >> 4) * 4 + r;
                float th = fkey_inv(runmax[rl]) - TAU;
#pragma unroll
                for (int aj = 0; aj < 4; ++aj) {
                    if (acc[ai][aj][r] >= th) {
                        unsigned idx = atomicAdd(&cnt[rl], 1u);
                        if (idx < CAP) cand[rl][idx] = (unsigned)(n0 + wc * 64 + aj * 16 + laneRow);
                    }
                }
            }
        }
        // next n0's first __syncthreads orders runmax/cand accesses
    }

    __syncthreads();
    if (tid < 128) cnt_g[m0 + tid] = min(cnt[tid], (unsigned)CAP);
    for (int i = tid; i < 128 * CAP; i += 512)
        cand_g[(size_t)(m0 + i / CAP) * CAP + (i % CAP)] = cand[i / CAP][i % CAP];
}

// ---------------- phase 2: exact fp32 rescore + gather ----------------
__global__ __launch_bounds__(256, 2)
void vq_phase2_kernel(const float* __restrict__ x, const float* __restrict__ embed,
                      const float* __restrict__ inv_norm,
                      const unsigned* __restrict__ cnt_g, const unsigned* __restrict__ cand_g,
                      float* __restrict__ out_q, float* __restrict__ out_i) {
    const int r    = blockIdx.x * 4 + (threadIdx.x >> 6);
    const int lane = threadIdx.x & 63;

    const float4 xa = *(const float4*)&x[(size_t)r * KDIM + lane * 8];
    const float4 xb = *(const float4*)&x[(size_t)r * KDIM + lane * 8 + 4];

    const int m = (int)cnt_g[r];
    float bestv = -3.4e38f;
    int   bestc = 0;
    for (int i = 0; i < m; ++i) {
        int c = (int)cand_g[(size_t)r * CAP + i];
        float inv = inv_norm[c];
        const float4 ea = *(const float4*)&embed[(size_t)c * KDIM + lane * 8];
        const float4 eb = *(const float4*)&embed[(size_t)c * KDIM + lane * 8 + 4];
        float s = 0.f;
        s = fmaf(xa.x, ea.x * inv, s); s = fmaf(xa.y, ea.y * inv, s);
        s = fmaf(xa.z, ea.z * inv, s); s = fmaf(xa.w, ea.w * inv, s);
        s = fmaf(xb.x, eb.x * inv, s); s = fmaf(xb.y, eb.y * inv, s);
        s = fmaf(xb.z, eb.z * inv, s); s = fmaf(xb.w, eb.w * inv, s);
#pragma unroll
        for (int off = 32; off >= 1; off >>= 1) s += __shfl_xor(s, off, 64);
        if (s > bestv || (s == bestv && c < bestc)) { bestv = s; bestc = c; }
    }

    if (lane == 0) out_i[r] = (float)bestc;
    const float4 qa = *(const float4*)&embed[(size_t)bestc * KDIM + lane * 8];
    const float4 qb = *(const float4*)&embed[(size_t)bestc * KDIM + lane * 8 + 4];
    *(float4*)&out_q[(size_t)r * KDIM + lane * 8]     = qa;
    *(float4*)&out_q[(size_t)r * KDIM + lane * 8 + 4] = qb;
}

// ================= fallback (round-2 kernel, known correct) =================
#define FBM   64
#define FBN   256
#define FBK   16

__global__ __launch_bounds__(256, 1)
void vq_norm_kernel(const float* __restrict__ embed, float* __restrict__ inv_norm) {
    const int row  = blockIdx.x * 4 + (threadIdx.x >> 6);
    const int lane = threadIdx.x & 63;
    const float* e = embed + (size_t)row * KDIM;
    float ss = 0.f;
#pragma unroll
    for (int p = 0; p < 8; ++p) { float v = e[lane + 64 * p]; ss = fmaf(v, v, ss); }
#pragma unroll
    for (int off = 32; off >= 1; off >>= 1) ss += __shfl_xor(ss, off, 64);
    if (lane == 0) inv_norm[row] = 1.0f / fmaxf(sqrtf(ss), 1e-12f);
}

__global__ __launch_bounds__(256, 2)
void vq_main_kernel(const float* __restrict__ x, const float* __restrict__ embed,
                    const float* __restrict__ inv_norm,
                    float* __restrict__ out_q, float* __restrict__ out_i) {
    __shared__ float As[FBK][FBM + 4];
    __shared__ float Bs[FBK][FBN + 4];
    __shared__ float best_val[FBM];
    __shared__ int   best_idx[FBM];
    const int tid = threadIdx.x;
    const int m0  = blockIdx.x * FBM;
    const int ty  = tid >> 5, tx = tid & 31;
    if (tid < FBM) { best_val[tid] = -3.0e38f; best_idx[tid] = 0; }
    const int am = tid >> 2, k4 = (tid & 3) << 2, bc = tid >> 2;
    float acc[8][8];
    for (int n0 = 0; n0 < CDIM; n0 += FBN) {
        float bs0 = inv_norm[n0+bc], bs1 = inv_norm[n0+bc+64], bs2 = inv_norm[n0+bc+128], bs3 = inv_norm[n0+bc+192];
#pragma unroll
        for (int i = 0; i < 8; ++i)
#pragma unroll
            for (int j = 0; j < 8; ++j) acc[i][j] = 0.f;
        float4 aReg = *(const float4*)&x[(size_t)(m0+am)*KDIM + k4];
        float4 b0 = *(const float4*)&embed[(size_t)(n0+bc)*KDIM + k4];
        float4 b1 = *(const float4*)&embed[(size_t)(n0+bc+64)*KDIM + k4];
        float4 b2 = *(const float4*)&embed[(size_t)(n0+bc+128)*KDIM + k4];
        float4 b3 = *(const float4*)&embed[(size_t)(n0+bc+192)*KDIM + k4];
        for (int kt = 0; kt < KDIM; kt += FBK) {
            __syncthreads();
            As[k4+0][am]=aReg.x; As[k4+1][am]=aReg.y; As[k4+2][am]=aReg.z; As[k4+3][am]=aReg.w;
            Bs[k4+0][bc]=b0.x*bs0; Bs[k4+1][bc]=b0.y*bs0; Bs[k4+2][bc]=b0.z*bs0; Bs[k4+3][bc]=b0.w*bs0;
            Bs[k4+0][bc+64]=b1.x*bs1; Bs[k4+1][bc+64]=b1.y*bs1; Bs[k4+2][bc+64]=b1.z*bs1; Bs[k4+3][bc+64]=b1.w*bs1;
            Bs[k4+0][bc+128]=b2.x*bs2; Bs[k4+1][bc+128]=b2.y*bs2; Bs[k4+2][bc+128]=b2.z*bs2; Bs[k4+3][bc+128]=b2.w*bs2;
            Bs[k4+0][bc+192]=b3.x*bs3; Bs[k4+1][bc+192]=b3.y*bs3; Bs[k4+2][bc+192]=b3.z*bs3; Bs[k4+3][bc+192]=b3.w*bs3;
            __syncthreads();
            if (kt + FBK < KDIM) {
                int kn = kt + FBK + k4;
                aReg = *(const float4*)&x[(size_t)(m0+am)*KDIM + kn];
                b0 = *(const float4*)&embed[(size_t)(n0+bc)*KDIM + kn];
                b1 = *(const float4*)&embed[(size_t)(n0+bc+64)*KDIM + kn];
                b2 = *(const float4*)&embed[(size_t)(n0+bc+128)*KDIM + kn];
                b3 = *(const float4*)&embed[(size_t)(n0+bc+192)*KDIM + kn];
            }
#pragma unroll 4
            for (int k = 0; k < FBK; ++k) {
                float a[8], b[8];
                *(float4*)&a[0] = *(const float4*)&As[k][ty*8];
                *(float4*)&a[4] = *(const float4*)&As[k][ty*8+4];
                *(float4*)&b[0] = *(const float4*)&Bs[k][tx*4];
                *(float4*)&b[4] = *(const float4*)&Bs[k][128+tx*4];
#pragma unroll
                for (int i = 0; i < 8; ++i)
#pragma unroll
                    for (int j = 0; j < 8; ++j) acc[i][j] = fmaf(a[i], b[j], acc[i][j]);
            }
        }
#pragma unroll
        for (int i = 0; i < 8; ++i) {
            float v = acc[i][0]; int jj = 0;
#pragma unroll
            for (int j = 1; j < 8; ++j) if (acc[i][j] > v) { v = acc[i][j]; jj = j; }
            int col = n0 + ((jj < 4) ? (tx*4+jj) : (128 + tx*4 + (jj-4)));
#pragma unroll
            for (int off = 16; off >= 1; off >>= 1) {
                float ov = __shfl_xor(v, off, 64);
                int   oc = __shfl_xor(col, off, 64);
                if (ov > v || (ov == v && oc < col)) { v = ov; col = oc; }
            }
            if (tx == 0) {
                int r = ty*8+i;
                if (v > best_val[r] || (v == best_val[r] && col < best_idx[r])) { best_val[r]=v; best_idx[r]=col; }
            }
        }
    }
    __syncthreads();
    if (tid < FBM) out_i[m0 + tid] = (float)best_idx[tid];
#pragma unroll 1
    for (int rp = 0; rp < FBM; rp += 2) {
        int r = rp + (tid >> 7), slot = tid & 127, src = best_idx[r];
        const float4 v = *(const float4*)&embed[(size_t)src*KDIM + slot*4];
        *(float4*)&out_q[(size_t)(m0+r)*KDIM + slot*4] = v;
    }
}

extern "C" void kernel_launch(void* const* d_in, const int* in_sizes, int n_in,
                              void* d_out, int out_size, void* d_ws, size_t ws_size,
                              hipStream_t stream) {
    const float* x     = (const float*)d_in[0];
    const float* embed = (const float*)d_in[1];
    float* out_q = (float*)d_out;
    float* out_i = (float*)d_out + (size_t)MTOT * KDIM;
    char*  ws    = (char*)d_ws;

    if (ws_size >= (size_t)WS_NEEDED) {
        unsigned short* xh  = (unsigned short*)(ws + XH_OFF);
        unsigned short* eh  = (unsigned short*)(ws + EH_OFF);
        float*          inv = (float*)(ws + INV_OFF);
        unsigned*       cnt = (unsigned*)(ws + CNT_OFF);
        unsigned*       cnd = (unsigned*)(ws + CAND_OFF);

        vq_norm_eh_kernel<<<CDIM / 4, 256, 0, stream>>>(embed, inv, eh);
        vq_convx_kernel<<<(MTOT * KDIM / 8) / 256, 256, 0, stream>>>(x, xh);
        vq_phase1_kernel<<<MTOT / 128, 512, 0, stream>>>(xh, eh, cnt, cnd);
        vq_phase2_kernel<<<MTOT / 4, 256, 0, stream>>>(x, embed, inv, cnt, cnd, out_q, out_i);
    } else {
        float* inv = (float*)ws;   // 8 KB
        vq_norm_kernel<<<CDIM / 4, 256, 0, stream>>>(embed, inv);
        vq_main_kernel<<<MTOT / FBM, 256, 0, stream>>>(x, embed, inv, out_q, out_i);
    }
}

// Round 4
// 180.878 us; speedup vs baseline: 5.5225x; 1.1188x over previous
//
#include <hip/hip_runtime.h>

#define MTOT 32768   // B*N
#define KDIM 512     // D
#define CDIM 2048    // C
#define CAP  16      // candidate slots per row
#define TAU  0.032f  // candidate window (~14 sigma of bf16 rounding noise)

// ---- workspace layout (bytes) ----
#define EH_OFF   0u
#define EH_SZ    (CDIM * KDIM * 2u)          // 2 MB bf16 normalized codebook
#define INV_OFF  (EH_OFF + EH_SZ)
#define INV_SZ   (CDIM * 4u)
#define CNT_OFF  (INV_OFF + INV_SZ)
#define CNT_SZ   (MTOT * 4u)
#define CAND_OFF (CNT_OFF + CNT_SZ)
#define CAND_SZ  (MTOT * CAP * 4u)
#define WS_NEEDED (CAND_OFF + CAND_SZ)

typedef short  short8 __attribute__((ext_vector_type(8)));
typedef float  f32x4  __attribute__((ext_vector_type(4)));

__device__ inline unsigned short f2bf(float f) {
    unsigned u = __float_as_uint(f);
    return (unsigned short)((u + 0x7FFFu + ((u >> 16) & 1u)) >> 16);  // RTNE
}
__device__ inline unsigned fkey(float f) {          // order-preserving f32->u32
    unsigned u = __float_as_uint(f);
    return (u & 0x80000000u) ? ~u : (u | 0x80000000u);
}
__device__ inline float fkey_inv(unsigned k) {
    unsigned u = (k & 0x80000000u) ? (k ^ 0x80000000u) : ~k;
    return __uint_as_float(u);
}

// ---------------- codebook norms + bf16 normalized codebook ----------------
__global__ __launch_bounds__(256, 1)
void vq_norm_eh_kernel(const float* __restrict__ embed, float* __restrict__ inv_norm,
                       unsigned short* __restrict__ eh) {
    const int row  = blockIdx.x * 4 + (threadIdx.x >> 6);
    const int lane = threadIdx.x & 63;
    const float4 v0 = *(const float4*)&embed[(size_t)row * KDIM + lane * 8];
    const float4 v1 = *(const float4*)&embed[(size_t)row * KDIM + lane * 8 + 4];
    float ss = v0.x*v0.x + v0.y*v0.y + v0.z*v0.z + v0.w*v0.w
             + v1.x*v1.x + v1.y*v1.y + v1.z*v1.z + v1.w*v1.w;
#pragma unroll
    for (int off = 32; off >= 1; off >>= 1) ss += __shfl_xor(ss, off, 64);
    float inv = 1.0f / fmaxf(sqrtf(ss), 1e-12f);
    if (lane == 0) inv_norm[row] = inv;
    short8 o;
    o[0] = (short)f2bf(v0.x * inv); o[1] = (short)f2bf(v0.y * inv);
    o[2] = (short)f2bf(v0.z * inv); o[3] = (short)f2bf(v0.w * inv);
    o[4] = (short)f2bf(v1.x * inv); o[5] = (short)f2bf(v1.y * inv);
    o[6] = (short)f2bf(v1.z * inv); o[7] = (short)f2bf(v1.w * inv);
    *(short8*)&eh[(size_t)row * KDIM + lane * 8] = o;
}

// ---------------- phase 1: bf16 MFMA GEMM + max + candidate window ----------------
// BM=64 rows/block (grid 512 -> 2 blocks/CU), BN=256 codes/tile, BK=64,
// 8 waves as 2(m)x4(n), wave tile 32x64 via 2x4 grid of 16x16x32 MFMA.
// A is read as fp32 x and converted to bf16 in-register during staging.
__global__ __launch_bounds__(512, 4)
void vq_phase1_kernel(const float* __restrict__ x,
                      const unsigned short* __restrict__ eh,
                      unsigned* __restrict__ cnt_g, unsigned* __restrict__ cand_g) {
    __shared__ char ldsA[64 * 128];    // 64 rows x 64 k x 2B (XOR-swizzled)  8 KB
    __shared__ char ldsB[256 * 128];   // 256 codes x 64 k x 2B              32 KB
    __shared__ unsigned runmax[64];
    __shared__ unsigned cnt[64];
    __shared__ unsigned cand[64][CAP];

    const int tid  = threadIdx.x;
    const int lane = tid & 63;
    const int wid  = tid >> 6;
    const int wr   = wid >> 2;          // 0..1
    const int wc   = wid & 3;           // 0..3
    const int m0   = blockIdx.x * 64;

    const int laneRow = lane & 15;
    const int laneK   = (lane >> 4) * 16;        // byte offset of k-chunk
    const int swz     = (laneRow & 7) << 4;

    if (tid < 64) { runmax[tid] = 0u; cnt[tid] = 0; }  // fkey of any finite > 0

    // staging geometry: A one short8-slot/thread, B four slots/thread
    const int aRow = tid >> 3;          // 0..63
    const int aK8  = tid & 7;           // 0..7
    const int aOff = (aRow * 128 + aK8 * 16) ^ ((aRow & 7) << 4);

    for (int n0 = 0; n0 < CDIM; n0 += 256) {
        f32x4 acc[2][4];
#pragma unroll
        for (int i = 0; i < 2; ++i)
#pragma unroll
            for (int j = 0; j < 4; ++j) acc[i][j] = (f32x4)0.0f;

        // prefetch kt=0
        float4 pa0 = *(const float4*)&x[(size_t)(m0 + aRow) * KDIM + aK8 * 8];
        float4 pa1 = *(const float4*)&x[(size_t)(m0 + aRow) * KDIM + aK8 * 8 + 4];
        short8 pb[4];
#pragma unroll
        for (int l = 0; l < 4; ++l) {
            int c = tid + l * 512, code = c >> 3, k8 = c & 7;
            pb[l] = *(const short8*)&eh[(size_t)(n0 + code) * KDIM + k8 * 8];
        }

        for (int kt = 0; kt < KDIM; kt += 64) {
            __syncthreads();
            {   // A: fp32 -> bf16 -> LDS
                short8 oa;
                oa[0] = (short)f2bf(pa0.x); oa[1] = (short)f2bf(pa0.y);
                oa[2] = (short)f2bf(pa0.z); oa[3] = (short)f2bf(pa0.w);
                oa[4] = (short)f2bf(pa1.x); oa[5] = (short)f2bf(pa1.y);
                oa[6] = (short)f2bf(pa1.z); oa[7] = (short)f2bf(pa1.w);
                *(short8*)(ldsA + aOff) = oa;
            }
#pragma unroll
            for (int l = 0; l < 4; ++l) {
                int c = tid + l * 512, code = c >> 3, k8 = c & 7;
                int off = (code * 128 + k8 * 16) ^ ((code & 7) << 4);
                *(short8*)(ldsB + off) = pb[l];
            }
            __syncthreads();

            if (kt + 64 < KDIM) {   // T14: prefetch next K-tile during MFMA
                int kn = kt + 64;
                pa0 = *(const float4*)&x[(size_t)(m0 + aRow) * KDIM + kn + aK8 * 8];
                pa1 = *(const float4*)&x[(size_t)(m0 + aRow) * KDIM + kn + aK8 * 8 + 4];
#pragma unroll
                for (int l = 0; l < 4; ++l) {
                    int c = tid + l * 512, code = c >> 3, k8 = c & 7;
                    pb[l] = *(const short8*)&eh[(size_t)(n0 + code) * KDIM + kn + k8 * 8];
                }
            }

#pragma unroll
            for (int kk = 0; kk < 2; ++kk) {
                short8 af[2], bf[4];
#pragma unroll
                for (int ai = 0; ai < 2; ++ai) {
                    int row = wr * 32 + ai * 16 + laneRow;
                    int off = ((row * 128 + laneK + kk * 64)) ^ swz;
                    af[ai] = *(const short8*)(ldsA + off);
                }
#pragma unroll
                for (int aj = 0; aj < 4; ++aj) {
                    int code = wc * 64 + aj * 16 + laneRow;
                    int off = ((code * 128 + laneK + kk * 64)) ^ swz;
                    bf[aj] = *(const short8*)(ldsB + off);
                }
#pragma unroll
                for (int ai = 0; ai < 2; ++ai)
#pragma unroll
                    for (int aj = 0; aj < 4; ++aj)
                        acc[ai][aj] = __builtin_amdgcn_mfma_f32_16x16x32_bf16(
                            af[ai], bf[aj], acc[ai][aj], 0, 0, 0);
            }
        }

        // per-row max -> runmax (row r = wr*32 + ai*16 + (lane>>4)*4 + reg)
#pragma unroll
        for (int ai = 0; ai < 2; ++ai) {
#pragma unroll
            for (int r = 0; r < 4; ++r) {
                float v = acc[ai][0][r];
                int   c = laneRow;
#pragma unroll
                for (int aj = 1; aj < 4; ++aj) {
                    float x2 = acc[ai][aj][r];
                    if (x2 > v) { v = x2; c = aj * 16 + laneRow; }
                }
#pragma unroll
                for (int off = 8; off >= 1; off >>= 1) {
                    float ov = __shfl_xor(v, off, 64);
                    int   oc = __shfl_xor(c, off, 64);
                    if (ov > v || (ov == v && oc < c)) { v = ov; c = oc; }
                }
                if (laneRow == 0) {
                    int rl = wr * 32 + ai * 16 + (lane >> 4) * 4 + r;
                    atomicMax(&runmax[rl], fkey(v));
                }
            }
        }
        __syncthreads();

        // candidate sweep against running max - TAU
#pragma unroll
        for (int ai = 0; ai < 2; ++ai) {
#pragma unroll
            for (int r = 0; r < 4; ++r) {
                int rl = wr * 32 + ai * 16 + (lane >> 4) * 4 + r;
                float th = fkey_inv(runmax[rl]) - TAU;
#pragma unroll
                for (int aj = 0; aj < 4; ++aj) {
                    if (acc[ai][aj][r] >= th) {
                        unsigned idx = atomicAdd(&cnt[rl], 1u);
                        if (idx < CAP) cand[rl][idx] = (unsigned)(n0 + wc * 64 + aj * 16 + laneRow);
                    }
                }
            }
        }
        // next n0's first __syncthreads orders runmax/cand accesses
    }

    __syncthreads();
    if (tid < 64) cnt_g[m0 + tid] = min(cnt[tid], (unsigned)CAP);
#pragma unroll
    for (int l = 0; l < 2; ++l) {
        int i = tid + l * 512;   // 64*CAP = 1024 words
        cand_g[(size_t)m0 * CAP + i] = cand[i / CAP][i % CAP];
    }
}

// ---------------- phase 2: exact fp32 rescore (rare) + gather ----------------
__global__ __launch_bounds__(256, 2)
void vq_phase2_kernel(const float* __restrict__ x, const float* __restrict__ embed,
                      const float* __restrict__ inv_norm,
                      const unsigned* __restrict__ cnt_g, const unsigned* __restrict__ cand_g,
                      float* __restrict__ out_q, float* __restrict__ out_i) {
    const int r    = blockIdx.x * 4 + (threadIdx.x >> 6);
    const int lane = threadIdx.x & 63;

    const int m = (int)cnt_g[r];
    int bestc;
    if (m <= 1) {
        bestc = (int)cand_g[(size_t)r * CAP];   // single candidate: no rescore
    } else {
        const float4 xa = *(const float4*)&x[(size_t)r * KDIM + lane * 8];
        const float4 xb = *(const float4*)&x[(size_t)r * KDIM + lane * 8 + 4];
        float bestv = -3.4e38f;
        bestc = 0;
        for (int i = 0; i < m; ++i) {
            int c = (int)cand_g[(size_t)r * CAP + i];
            float inv = inv_norm[c];
            const float4 ea = *(const float4*)&embed[(size_t)c * KDIM + lane * 8];
            const float4 eb = *(const float4*)&embed[(size_t)c * KDIM + lane * 8 + 4];
            float s = 0.f;
            s = fmaf(xa.x, ea.x * inv, s); s = fmaf(xa.y, ea.y * inv, s);
            s = fmaf(xa.z, ea.z * inv, s); s = fmaf(xa.w, ea.w * inv, s);
            s = fmaf(xb.x, eb.x * inv, s); s = fmaf(xb.y, eb.y * inv, s);
            s = fmaf(xb.z, eb.z * inv, s); s = fmaf(xb.w, eb.w * inv, s);
#pragma unroll
            for (int off = 32; off >= 1; off >>= 1) s += __shfl_xor(s, off, 64);
            if (s > bestv || (s == bestv && c < bestc)) { bestv = s; bestc = c; }
        }
    }

    if (lane == 0) out_i[r] = (float)bestc;
    const float4 qa = *(const float4*)&embed[(size_t)bestc * KDIM + lane * 8];
    const float4 qb = *(const float4*)&embed[(size_t)bestc * KDIM + lane * 8 + 4];
    *(float4*)&out_q[(size_t)r * KDIM + lane * 8]     = qa;
    *(float4*)&out_q[(size_t)r * KDIM + lane * 8 + 4] = qb;
}

// ================= fallback (round-2 kernel, known correct) =================
#define FBM   64
#define FBN   256
#define FBK   16

__global__ __launch_bounds__(256, 1)
void vq_norm_kernel(const float* __restrict__ embed, float* __restrict__ inv_norm) {
    const int row  = blockIdx.x * 4 + (threadIdx.x >> 6);
    const int lane = threadIdx.x & 63;
    const float* e = embed + (size_t)row * KDIM;
    float ss = 0.f;
#pragma unroll
    for (int p = 0; p < 8; ++p) { float v = e[lane + 64 * p]; ss = fmaf(v, v, ss); }
#pragma unroll
    for (int off = 32; off >= 1; off >>= 1) ss += __shfl_xor(ss, off, 64);
    if (lane == 0) inv_norm[row] = 1.0f / fmaxf(sqrtf(ss), 1e-12f);
}

__global__ __launch_bounds__(256, 2)
void vq_main_kernel(const float* __restrict__ x, const float* __restrict__ embed,
                    const float* __restrict__ inv_norm,
                    float* __restrict__ out_q, float* __restrict__ out_i) {
    __shared__ float As[FBK][FBM + 4];
    __shared__ float Bs[FBK][FBN + 4];
    __shared__ float best_val[FBM];
    __shared__ int   best_idx[FBM];
    const int tid = threadIdx.x;
    const int m0  = blockIdx.x * FBM;
    const int ty  = tid >> 5, tx = tid & 31;
    if (tid < FBM) { best_val[tid] = -3.0e38f; best_idx[tid] = 0; }
    const int am = tid >> 2, k4 = (tid & 3) << 2, bc = tid >> 2;
    float acc[8][8];
    for (int n0 = 0; n0 < CDIM; n0 += FBN) {
        float bs0 = inv_norm[n0+bc], bs1 = inv_norm[n0+bc+64], bs2 = inv_norm[n0+bc+128], bs3 = inv_norm[n0+bc+192];
#pragma unroll
        for (int i = 0; i < 8; ++i)
#pragma unroll
            for (int j = 0; j < 8; ++j) acc[i][j] = 0.f;
        float4 aReg = *(const float4*)&x[(size_t)(m0+am)*KDIM + k4];
        float4 b0 = *(const float4*)&embed[(size_t)(n0+bc)*KDIM + k4];
        float4 b1 = *(const float4*)&embed[(size_t)(n0+bc+64)*KDIM + k4];
        float4 b2 = *(const float4*)&embed[(size_t)(n0+bc+128)*KDIM + k4];
        float4 b3 = *(const float4*)&embed[(size_t)(n0+bc+192)*KDIM + k4];
        for (int kt = 0; kt < KDIM; kt += FBK) {
            __syncthreads();
            As[k4+0][am]=aReg.x; As[k4+1][am]=aReg.y; As[k4+2][am]=aReg.z; As[k4+3][am]=aReg.w;
            Bs[k4+0][bc]=b0.x*bs0; Bs[k4+1][bc]=b0.y*bs0; Bs[k4+2][bc]=b0.z*bs0; Bs[k4+3][bc]=b0.w*bs0;
            Bs[k4+0][bc+64]=b1.x*bs1; Bs[k4+1][bc+64]=b1.y*bs1; Bs[k4+2][bc+64]=b1.z*bs1; Bs[k4+3][bc+64]=b1.w*bs1;
            Bs[k4+0][bc+128]=b2.x*bs2; Bs[k4+1][bc+128]=b2.y*bs2; Bs[k4+2][bc+128]=b2.z*bs2; Bs[k4+3][bc+128]=b2.w*bs2;
            Bs[k4+0][bc+192]=b3.x*bs3; Bs[k4+1][bc+192]=b3.y*bs3; Bs[k4+2][bc+192]=b3.z*bs3; Bs[k4+3][bc+192]=b3.w*bs3;
            __syncthreads();
            if (kt + FBK < KDIM) {
                int kn = kt + FBK + k4;
                aReg = *(const float4*)&x[(size_t)(m0+am)*KDIM + kn];
                b0 = *(const float4*)&embed[(size_t)(n0+bc)*KDIM + kn];
                b1 = *(const float4*)&embed[(size_t)(n0+bc+64)*KDIM + kn];
                b2 = *(const float4*)&embed[(size_t)(n0+bc+128)*KDIM + kn];
                b3 = *(const float4*)&embed[(size_t)(n0+bc+192)*KDIM + kn];
            }
#pragma unroll 4
            for (int k = 0; k < FBK; ++k) {
                float a[8], b[8];
                *(float4*)&a[0] = *(const float4*)&As[k][ty*8];
                *(float4*)&a[4] = *(const float4*)&As[k][ty*8+4];
                *(float4*)&b[0] = *(const float4*)&Bs[k][tx*4];
                *(float4*)&b[4] = *(const float4*)&Bs[k][128+tx*4];
#pragma unroll
                for (int i = 0; i < 8; ++i)
#pragma unroll
                    for (int j = 0; j < 8; ++j) acc[i][j] = fmaf(a[i], b[j], acc[i][j]);
            }
        }
#pragma unroll
        for (int i = 0; i < 8; ++i) {
            float v = acc[i][0]; int jj = 0;
#pragma unroll
            for (int j = 1; j < 8; ++j) if (acc[i][j] > v) { v = acc[i][j]; jj = j; }
            int col = n0 + ((jj < 4) ? (tx*4+jj) : (128 + tx*4 + (jj-4)));
#pragma unroll
            for (int off = 16; off >= 1; off >>= 1) {
                float ov = __shfl_xor(v, off, 64);
                int   oc = __shfl_xor(col, off, 64);
                if (ov > v || (ov == v && oc < col)) { v = ov; col = oc; }
            }
            if (tx == 0) {
                int r = ty*8+i;
                if (v > best_val[r] || (v == best_val[r] && col < best_idx[r])) { best_val[r]=v; best_idx[r]=col; }
            }
        }
    }
    __syncthreads();
    if (tid < FBM) out_i[m0 + tid] = (float)best_idx[tid];
#pragma unroll 1
    for (int rp = 0; rp < FBM; rp += 2) {
        int r = rp + (tid >> 7), slot = tid & 127, src = best_idx[r];
        const float4 v = *(const float4*)&embed[(size_t)src*KDIM + slot*4];
        *(float4*)&out_q[(size_t)(m0+r)*KDIM + slot*4] = v;
    }
}

extern "C" void kernel_launch(void* const* d_in, const int* in_sizes, int n_in,
                              void* d_out, int out_size, void* d_ws, size_t ws_size,
                              hipStream_t stream) {
    const float* x     = (const float*)d_in[0];
    const float* embed = (const float*)d_in[1];
    float* out_q = (float*)d_out;
    float* out_i = (float*)d_out + (size_t)MTOT * KDIM;
    char*  ws    = (char*)d_ws;

    if (ws_size >= (size_t)WS_NEEDED) {
        unsigned short* eh  = (unsigned short*)(ws + EH_OFF);
        float*          inv = (float*)(ws + INV_OFF);
        unsigned*       cnt = (unsigned*)(ws + CNT_OFF);
        unsigned*       cnd = (unsigned*)(ws + CAND_OFF);

        vq_norm_eh_kernel<<<CDIM / 4, 256, 0, stream>>>(embed, inv, eh);
        vq_phase1_kernel<<<MTOT / 64, 512, 0, stream>>>(x, eh, cnt, cnd);
        vq_phase2_kernel<<<MTOT / 4, 256, 0, stream>>>(x, embed, inv, cnt, cnd, out_q, out_i);
    } else {
        float* inv = (float*)ws;   // 8 KB
        vq_norm_kernel<<<CDIM / 4, 256, 0, stream>>>(embed, inv);
        vq_main_kernel<<<MTOT / FBM, 256, 0, stream>>>(x, embed, inv, out_q, out_i);
    }
}